// Round 27
// baseline (536.012 us; speedup 1.0000x reference)
//
#include <hip/hip_runtime.h>
#include <hip/hip_bf16.h>
#include <math.h>

#define H_ 16
#define E_ 8
#define D_ 1024
#define P_ 64
#define PV_ 64
#define B_ 8
#define T_ 512
#define R_ 1023
#define BT_ 4096
#define CAP_ 1024
#define PROWS_ 192
#define PTILES_ 4

typedef __attribute__((ext_vector_type(8))) unsigned short ushort8;
typedef __attribute__((ext_vector_type(4))) unsigned short ushort4v;
typedef __attribute__((ext_vector_type(8))) short short8;
typedef __attribute__((ext_vector_type(4))) float f32x4;

__device__ inline float bf2f(unsigned short u) {
  union { unsigned int i; float f; } c; c.i = ((unsigned int)u) << 16; return c.f;
}
__device__ inline unsigned short f2bf(float f) {
  __hip_bfloat16 h = __float2bfloat16(f);
  return *reinterpret_cast<unsigned short*>(&h);
}

// ---------------------------------------------------------------- zero counts
__global__ void zero_cnt_kernel(int* __restrict__ cnt) {
  int i = threadIdx.x;
  if (i < 512) cnt[i] = 0;
}

// ---------------------------------------------------------------- x -> bf16
__global__ __launch_bounds__(256) void xcvt_kernel(
    const float* __restrict__ x, unsigned short* __restrict__ xbu) {
  int i = blockIdx.x * 256 + threadIdx.x;  // over 1M float4
  float4 w = ((const float4*)x)[i];
  ushort4v o = {f2bf(w.x), f2bf(w.y), f2bf(w.z), f2bf(w.w)};
  *(ushort4v*)&xbu[(size_t)i * 4] = o;
}

// ---------------------------------------------------------------- weight -> bf16
// flat convert of 8.4M floats (one HxE x D x P weight).
__global__ __launch_bounds__(256) void wcvt_kernel(
    const float* __restrict__ w, unsigned short* __restrict__ wb) {
  int i = blockIdx.x * 256 + threadIdx.x;  // over 2M float4
  float4 v = ((const float4*)w)[i];
  ushort4v o = {f2bf(v.x), f2bf(v.y), f2bf(v.z), f2bf(v.w)};
  *(ushort4v*)&wb[(size_t)i * 4] = o;
}

// ---------------------------------------------------------------- w_sel transpose
__global__ __launch_bounds__(256) void wt_transpose_kernel(
    const float* __restrict__ wso, const float* __restrict__ wsv,
    float* __restrict__ wt) {
  __shared__ float tb[64][65];
  int ct = blockIdx.x, kt = blockIdx.y;  // (4, 16)
  int tid = threadIdx.x;
  int cl = tid >> 2, kseg = (tid & 3) * 16;
  int c = ct * 64 + cl;
  const float* src = (c < 128) ? (wso + (size_t)c * D_)
                               : (wsv + (size_t)(c - 128) * D_);
#pragma unroll
  for (int i = 0; i < 4; ++i) {
    float4 v4 = *(const float4*)&src[kt * 64 + kseg + i * 4];
    tb[cl][kseg + i * 4 + 0] = v4.x;
    tb[cl][kseg + i * 4 + 1] = v4.y;
    tb[cl][kseg + i * 4 + 2] = v4.z;
    tb[cl][kseg + i * 4 + 3] = v4.w;
  }
  __syncthreads();
  int kl = tid >> 2, cseg = (tid & 3) * 16;
#pragma unroll
  for (int i = 0; i < 4; ++i) {
    float4 o = {tb[cseg + i * 4 + 0][kl], tb[cseg + i * 4 + 1][kl],
                tb[cseg + i * 4 + 2][kl], tb[cseg + i * 4 + 3][kl]};
    *(float4*)&wt[(size_t)(kt * 64 + kl) * 256 + ct * 64 + cseg + i * 4] = o;
  }
}

// ---------------------------------------------------------------- gates GEMM v4
__global__ __launch_bounds__(256) void gates_gemm(
    const float* __restrict__ x, const float* __restrict__ wt,
    float* __restrict__ part) {
  __shared__ __align__(16) float xs[32][256];  // 32 KB
  int tid = threadIdx.x;
  int bt0 = blockIdx.x * 32;
  int ks = blockIdx.y;

  {
    const float4* xr = (const float4*)x;
#pragma unroll
    for (int p = 0; p < 8; ++p) {
      int idx = p * 256 + tid;
      int r = idx >> 6, k4 = idx & 63;
      ((float4*)xs[r])[k4] = xr[(size_t)(bt0 + r) * 256 + ks * 64 + k4];
    }
  }
  __syncthreads();

  int wave = tid >> 6, lane = tid & 63;
  const float4* wt4 = (const float4*)wt + (size_t)ks * 256 * 64 + lane;
  float4 acc[8];
#pragma unroll
  for (int r = 0; r < 8; ++r) acc[r] = (float4){0.f, 0.f, 0.f, 0.f};

  for (int k4b = 0; k4b < 64; ++k4b) {
    float4 wv0 = wt4[(size_t)(k4b * 4 + 0) * 64];
    float4 wv1 = wt4[(size_t)(k4b * 4 + 1) * 64];
    float4 wv2 = wt4[(size_t)(k4b * 4 + 2) * 64];
    float4 wv3 = wt4[(size_t)(k4b * 4 + 3) * 64];
#pragma unroll
    for (int r = 0; r < 8; ++r) {
      float4 xv = ((const float4*)xs[wave * 8 + r])[k4b];
      acc[r].x += xv.x * wv0.x + xv.y * wv1.x + xv.z * wv2.x + xv.w * wv3.x;
      acc[r].y += xv.x * wv0.y + xv.y * wv1.y + xv.z * wv2.y + xv.w * wv3.y;
      acc[r].z += xv.x * wv0.z + xv.y * wv1.z + xv.z * wv2.z + xv.w * wv3.z;
      acc[r].w += xv.x * wv0.w + xv.y * wv1.w + xv.z * wv2.w + xv.w * wv3.w;
    }
  }

#pragma unroll
  for (int r = 0; r < 8; ++r)
    *(float4*)&part[((size_t)(bt0 + wave * 8 + r) * 4 + ks) * 256 + lane * 4] =
        acc[r];
}

// ---------------------------------------------------------------- gates combine
__global__ __launch_bounds__(256) void gates_combine(
    const float* __restrict__ part, int* __restrict__ cnt,
    int* __restrict__ lidx, float* __restrict__ lg,
    float* __restrict__ coefs) {
  __shared__ float gv[8][2][H_][E_];
  int tid = threadIdx.x;
  int bt0 = blockIdx.x * 8;

  {
    int set = tid >> 7, he = tid & 127;
    int h = he >> 3, e = he & 7;
#pragma unroll
    for (int r = 0; r < 8; ++r) {
      const float* p = &part[(size_t)(bt0 + r) * 4 * 256 + tid];
      float v = ((p[0] + p[256]) + p[512]) + p[768];
      gv[r][set][h][e] = 1.f / (1.f + expf(-v));
    }
  }
  __syncthreads();

  {
    int r = tid >> 5, st = (tid >> 4) & 1, hh = tid & 15;
    int bt = bt0 + r;
    const float* g = gv[r][st][hh];
    int i1 = 0; float v1 = g[0];
    for (int ee = 1; ee < 8; ee++) if (g[ee] > v1) { v1 = g[ee]; i1 = ee; }
    int i2 = (i1 == 0) ? 1 : 0; float v2 = g[i2];
    for (int ee = 0; ee < 8; ee++) {
      if (ee == i1) continue;
      if (g[ee] > v2) { v2 = g[ee]; i2 = ee; }
    }
    int base1 = ((st * H_ + hh) * E_ + i1) * 2 + 0;
    int p1 = atomicAdd(&cnt[base1], 1);
    lidx[(size_t)base1 * CAP_ + p1] = bt;
    lg[(size_t)base1 * CAP_ + p1] = v1;
    int base2 = ((st * H_ + hh) * E_ + i2) * 2 + 1;
    int p2 = atomicAdd(&cnt[base2], 1);
    lidx[(size_t)base2 * CAP_ + p2] = bt;
    lg[(size_t)base2 * CAP_ + p2] = v2;
    if (st == 0) {
#pragma unroll
      for (int ee = 0; ee < 8; ee++) {
        float c = (ee == i1) ? v1 : ((ee == i2) ? v2 : 0.f);
        coefs[((size_t)bt * H_ + hh) * E_ + ee] = c;
      }
    }
  }
}

// ---------------------------------------------------------------- proj both slots (fp32 B)
__global__ __launch_bounds__(256) void proj_q2_mfma(
    const unsigned short* __restrict__ xb, const float* __restrict__ W,
    const int* __restrict__ cnt, const int* __restrict__ lidx,
    const float* __restrict__ lg, unsigned short* __restrict__ out0,
    unsigned short* __restrict__ out1, int set) {
  int he = blockIdx.x, tile = blockIdx.y;
  int base0 = (set * 128 + he) * 2 + 0, base1 = (set * 128 + he) * 2 + 1;
  int n0 = cnt[base0], n1 = cnt[base1];
  int start = tile * PROWS_;
  if (start >= n0 && start >= n1) return;
  int m0 = min(PROWS_, max(0, n0 - start));
  int m1 = min(PROWS_, max(0, n1 - start));

  __shared__ int ridx0[PROWS_], ridx1[PROWS_];
  __shared__ float rgs0[PROWS_], rgs1[PROWS_];
  __shared__ __align__(16) unsigned short As0[PROWS_][72];
  __shared__ __align__(16) unsigned short As1[PROWS_][72];
  __shared__ __align__(16) unsigned short Bs[64][72];
  int tid = threadIdx.x;
  for (int i = tid; i < PROWS_; i += 256) {
    int v0i = 0, v1i = 0; float g0 = 0.f, g1 = 0.f;
    if (i < m0) {
      v0i = lidx[(size_t)base0 * CAP_ + start + i];
      g0 = lg[(size_t)base0 * CAP_ + start + i];
    }
    if (i < m1) {
      v1i = lidx[(size_t)base1 * CAP_ + start + i];
      g1 = lg[(size_t)base1 * CAP_ + start + i];
    }
    ridx0[i] = v0i; rgs0[i] = g0;
    ridx1[i] = v1i; rgs1[i] = g1;
  }
  __syncthreads();

  int wave = tid >> 6, lane = tid & 63;
  int lr = lane & 15, lk = (lane >> 4) << 3;
  f32x4 acc0[3][4] = {}, acc1[3][4] = {};
  const float* Wb = W + (size_t)he * D_ * P_;

  int sr = tid >> 2, sseg = (tid & 3) << 4;
  int c4 = (tid & 15) * 4;
  int drb = tid >> 4;

  for (int d0 = 0; d0 < D_; d0 += 64) {
#pragma unroll
    for (int i = 0; i < 3; ++i) {
      int row = i * 64 + sr;
      const unsigned short* x0 = xb + (size_t)ridx0[row] * D_ + d0 + sseg;
      *(ushort8*)&As0[row][sseg] = *(const ushort8*)x0;
      *(ushort8*)&As0[row][sseg + 8] = *(const ushort8*)(x0 + 8);
      const unsigned short* x1 = xb + (size_t)ridx1[row] * D_ + d0 + sseg;
      *(ushort8*)&As1[row][sseg] = *(const ushort8*)x1;
      *(ushort8*)&As1[row][sseg + 8] = *(const ushort8*)(x1 + 8);
    }
#pragma unroll
    for (int pass = 0; pass < 4; ++pass) {
      int dr = pass * 16 + drb;
      float4 wv = *(const float4*)&Wb[(size_t)(d0 + dr) * P_ + c4];
      Bs[c4 + 0][dr] = f2bf(wv.x);
      Bs[c4 + 1][dr] = f2bf(wv.y);
      Bs[c4 + 2][dr] = f2bf(wv.z);
      Bs[c4 + 3][dr] = f2bf(wv.w);
    }
    __syncthreads();
#pragma unroll
    for (int kk = 0; kk < 2; ++kk) {
      short8 af0[3], af1[3], bfr[4];
#pragma unroll
      for (int mm = 0; mm < 3; ++mm) {
        af0[mm] = *(const short8*)&As0[wave * 48 + mm * 16 + lr][kk * 32 + lk];
        af1[mm] = *(const short8*)&As1[wave * 48 + mm * 16 + lr][kk * 32 + lk];
      }
#pragma unroll
      for (int nn = 0; nn < 4; ++nn)
        bfr[nn] = *(const short8*)&Bs[nn * 16 + lr][kk * 32 + lk];
#pragma unroll
      for (int mm = 0; mm < 3; ++mm)
#pragma unroll
        for (int nn = 0; nn < 4; ++nn) {
          acc0[mm][nn] = __builtin_amdgcn_mfma_f32_16x16x32_bf16(
              af0[mm], bfr[nn], acc0[mm][nn], 0, 0, 0);
          acc1[mm][nn] = __builtin_amdgcn_mfma_f32_16x16x32_bf16(
              af1[mm], bfr[nn], acc1[mm][nn], 0, 0, 0);
        }
    }
    __syncthreads();
  }

  int h = he >> 3;
#pragma unroll
  for (int mm = 0; mm < 3; ++mm) {
#pragma unroll
    for (int r = 0; r < 4; ++r) {
      int row = wave * 48 + mm * 16 + (lane >> 4) * 4 + r;
      if (row < m0) {
        int bt = ridx0[row]; float g = rgs0[row];
        int b = bt >> 9, t = bt & 511;
        unsigned short* orow = out0 + ((size_t)((b * H_ + h) * T_) + t) * P_;
#pragma unroll
        for (int nn = 0; nn < 4; ++nn)
          orow[nn * 16 + lr] = f2bf(g * acc0[mm][nn][r]);
      }
      if (row < m1) {
        int bt = ridx1[row]; float g = rgs1[row];
        int b = bt >> 9, t = bt & 511;
        unsigned short* orow = out1 + ((size_t)((b * H_ + h) * T_) + t) * P_;
#pragma unroll
        for (int nn = 0; nn < 4; ++nn)
          orow[nn * 16 + lr] = f2bf(g * acc1[mm][nn][r]);
      }
    }
  }
}

// ---------------------------------------------------------------- proj both slots (bf16 B)
// Identical structure; B source is pre-converted bf16 -> no f2bf chain, 8B loads.
__global__ __launch_bounds__(256) void proj_q2h_mfma(
    const unsigned short* __restrict__ xb, const unsigned short* __restrict__ Wh,
    const int* __restrict__ cnt, const int* __restrict__ lidx,
    const float* __restrict__ lg, unsigned short* __restrict__ out0,
    unsigned short* __restrict__ out1, int set) {
  int he = blockIdx.x, tile = blockIdx.y;
  int base0 = (set * 128 + he) * 2 + 0, base1 = (set * 128 + he) * 2 + 1;
  int n0 = cnt[base0], n1 = cnt[base1];
  int start = tile * PROWS_;
  if (start >= n0 && start >= n1) return;
  int m0 = min(PROWS_, max(0, n0 - start));
  int m1 = min(PROWS_, max(0, n1 - start));

  __shared__ int ridx0[PROWS_], ridx1[PROWS_];
  __shared__ float rgs0[PROWS_], rgs1[PROWS_];
  __shared__ __align__(16) unsigned short As0[PROWS_][72];
  __shared__ __align__(16) unsigned short As1[PROWS_][72];
  __shared__ __align__(16) unsigned short Bs[64][72];
  int tid = threadIdx.x;
  for (int i = tid; i < PROWS_; i += 256) {
    int v0i = 0, v1i = 0; float g0 = 0.f, g1 = 0.f;
    if (i < m0) {
      v0i = lidx[(size_t)base0 * CAP_ + start + i];
      g0 = lg[(size_t)base0 * CAP_ + start + i];
    }
    if (i < m1) {
      v1i = lidx[(size_t)base1 * CAP_ + start + i];
      g1 = lg[(size_t)base1 * CAP_ + start + i];
    }
    ridx0[i] = v0i; rgs0[i] = g0;
    ridx1[i] = v1i; rgs1[i] = g1;
  }
  __syncthreads();

  int wave = tid >> 6, lane = tid & 63;
  int lr = lane & 15, lk = (lane >> 4) << 3;
  f32x4 acc0[3][4] = {}, acc1[3][4] = {};
  const unsigned short* Whb = Wh + (size_t)he * D_ * P_;

  int sr = tid >> 2, sseg = (tid & 3) << 4;
  int c4 = (tid & 15) * 4;
  int drb = tid >> 4;

  for (int d0 = 0; d0 < D_; d0 += 64) {
#pragma unroll
    for (int i = 0; i < 3; ++i) {
      int row = i * 64 + sr;
      const unsigned short* x0 = xb + (size_t)ridx0[row] * D_ + d0 + sseg;
      *(ushort8*)&As0[row][sseg] = *(const ushort8*)x0;
      *(ushort8*)&As0[row][sseg + 8] = *(const ushort8*)(x0 + 8);
      const unsigned short* x1 = xb + (size_t)ridx1[row] * D_ + d0 + sseg;
      *(ushort8*)&As1[row][sseg] = *(const ushort8*)x1;
      *(ushort8*)&As1[row][sseg + 8] = *(const ushort8*)(x1 + 8);
    }
#pragma unroll
    for (int pass = 0; pass < 4; ++pass) {
      int dr = pass * 16 + drb;
      ushort4v wv = *(const ushort4v*)&Whb[(size_t)(d0 + dr) * P_ + c4];
      Bs[c4 + 0][dr] = wv[0];
      Bs[c4 + 1][dr] = wv[1];
      Bs[c4 + 2][dr] = wv[2];
      Bs[c4 + 3][dr] = wv[3];
    }
    __syncthreads();
#pragma unroll
    for (int kk = 0; kk < 2; ++kk) {
      short8 af0[3], af1[3], bfr[4];
#pragma unroll
      for (int mm = 0; mm < 3; ++mm) {
        af0[mm] = *(const short8*)&As0[wave * 48 + mm * 16 + lr][kk * 32 + lk];
        af1[mm] = *(const short8*)&As1[wave * 48 + mm * 16 + lr][kk * 32 + lk];
      }
#pragma unroll
      for (int nn = 0; nn < 4; ++nn)
        bfr[nn] = *(const short8*)&Bs[nn * 16 + lr][kk * 32 + lk];
#pragma unroll
      for (int mm = 0; mm < 3; ++mm)
#pragma unroll
        for (int nn = 0; nn < 4; ++nn) {
          acc0[mm][nn] = __builtin_amdgcn_mfma_f32_16x16x32_bf16(
              af0[mm], bfr[nn], acc0[mm][nn], 0, 0, 0);
          acc1[mm][nn] = __builtin_amdgcn_mfma_f32_16x16x32_bf16(
              af1[mm], bfr[nn], acc1[mm][nn], 0, 0, 0);
        }
    }
    __syncthreads();
  }

  int h = he >> 3;
#pragma unroll
  for (int mm = 0; mm < 3; ++mm) {
#pragma unroll
    for (int r = 0; r < 4; ++r) {
      int row = wave * 48 + mm * 16 + (lane >> 4) * 4 + r;
      if (row < m0) {
        int bt = ridx0[row]; float g = rgs0[row];
        int b = bt >> 9, t = bt & 511;
        unsigned short* orow = out0 + ((size_t)((b * H_ + h) * T_) + t) * P_;
#pragma unroll
        for (int nn = 0; nn < 4; ++nn)
          orow[nn * 16 + lr] = f2bf(g * acc0[mm][nn][r]);
      }
      if (row < m1) {
        int bt = ridx1[row]; float g = rgs1[row];
        int b = bt >> 9, t = bt & 511;
        unsigned short* orow = out1 + ((size_t)((b * H_ + h) * T_) + t) * P_;
#pragma unroll
        for (int nn = 0; nn < 4; ++nn)
          orow[nn * 16 + lr] = f2bf(g * acc1[mm][nn][r]);
      }
    }
  }
}

// ---------------------------------------------------------------- pe/Wpos -> bf16
__global__ __launch_bounds__(256) void cvt_pos_kernel(
    const float* __restrict__ pe, const float* __restrict__ Wp,
    unsigned short* __restrict__ peb, unsigned short* __restrict__ wpb) {
  int bid = blockIdx.x;
  const float* src;
  unsigned short* dst;
  if (bid < R_) { src = pe + (size_t)bid * D_; dst = peb + (size_t)bid * D_; }
  else { src = Wp + (size_t)(bid - R_) * D_; dst = wpb + (size_t)(bid - R_) * D_; }
  int tid = threadIdx.x;
  float4 w = ((const float4*)src)[tid];
  ushort4v o = {f2bf(w.x), f2bf(w.y), f2bf(w.z), f2bf(w.w)};
  *(ushort4v*)&dst[tid * 4] = o;
}

// ---------------------------------------------------------------- k_pos MFMA v2
__global__ __launch_bounds__(256) void kpos_mfma(
    const unsigned short* __restrict__ peb, const unsigned short* __restrict__ wpb,
    unsigned short* __restrict__ kposb) {
  __shared__ __align__(16) unsigned short As[64][72];
  __shared__ __align__(16) unsigned short Bs[64][72];
  int tid = threadIdx.x, mt = blockIdx.x, nt = blockIdx.y;
  int wave = tid >> 6, lane = tid & 63;
  int wr = wave >> 1, wc = wave & 1;
  int lrow = lane & 15, lk = (lane >> 4) << 3;
  f32x4 acc[2][2] = {};
  int sr = tid >> 2, sseg = (tid & 3) << 4;

  for (int d0 = 0; d0 < D_; d0 += 64) {
    {
      const unsigned short* arow = &peb[(size_t)(mt * 64 + sr) * D_ + d0 + sseg];
      *(ushort8*)&As[sr][sseg] = *(const ushort8*)arow;
      *(ushort8*)&As[sr][sseg + 8] = *(const ushort8*)(arow + 8);
      const unsigned short* brow = &wpb[(size_t)(nt * 64 + sr) * D_ + d0 + sseg];
      *(ushort8*)&Bs[sr][sseg] = *(const ushort8*)brow;
      *(ushort8*)&Bs[sr][sseg + 8] = *(const ushort8*)(brow + 8);
    }
    __syncthreads();
#pragma unroll
    for (int kk = 0; kk < 2; ++kk) {
      short8 af[2], bfr[2];
#pragma unroll
      for (int mm = 0; mm < 2; ++mm)
        af[mm] = *(const short8*)&As[wr * 32 + mm * 16 + lrow][kk * 32 + lk];
#pragma unroll
      for (int nn = 0; nn < 2; ++nn)
        bfr[nn] = *(const short8*)&Bs[wc * 32 + nn * 16 + lrow][kk * 32 + lk];
#pragma unroll
      for (int mm = 0; mm < 2; ++mm)
#pragma unroll
        for (int nn = 0; nn < 2; ++nn)
          acc[mm][nn] = __builtin_amdgcn_mfma_f32_16x16x32_bf16(
              af[mm], bfr[nn], acc[mm][nn], 0, 0, 0);
    }
    __syncthreads();
  }

  int orow0 = mt * 64 + wr * 32 + (lane >> 4) * 4;
  int ocol0 = nt * 64 + wc * 32 + lrow;
#pragma unroll
  for (int mm = 0; mm < 2; ++mm)
#pragma unroll
    for (int nn = 0; nn < 2; ++nn)
#pragma unroll
      for (int r = 0; r < 4; ++r)
        kposb[(size_t)(orow0 + mm * 16 + r) * 1024 + ocol0 + nn * 16] =
            f2bf(acc[mm][nn][r]);
}

// ---------------------------------------------------------------- attention (MFMA flash)
// q = q0+q1, k = k0+k1, v = v0+v1 (summed while staging).
__global__ __launch_bounds__(256) void attn_mfma(
    const unsigned short* __restrict__ q0, const unsigned short* __restrict__ q1,
    const unsigned short* __restrict__ k0, const unsigned short* __restrict__ k1,
    const unsigned short* __restrict__ v0, const unsigned short* __restrict__ v1,
    const unsigned short* __restrict__ kposb, unsigned short* __restrict__ ctx) {
  int b = blockIdx.x, h = blockIdx.y, qt = blockIdx.z;
  int t0 = qt << 6;
  int tid = threadIdx.x, wave = tid >> 6, lane = tid & 63;
  int lr = lane & 15, lkg = lane >> 4;
  int lk = lkg << 3;

  __shared__ __align__(16) unsigned short Ks[64][72];
  __shared__ __align__(16) unsigned short VTs[64][72];
  __shared__ __align__(16) unsigned short Srl[64][136];

  size_t bh = (size_t)(b * H_ + h);
  const unsigned short* kb0 = k0 + bh * T_ * 64;
  const unsigned short* kb1 = k1 + bh * T_ * 64;
  const unsigned short* vb0 = v0 + bh * T_ * 64;
  const unsigned short* vb1 = v1 + bh * T_ * 64;

  short8 qf[2];
  {
    size_t qoff = (bh * T_ + (size_t)(t0 + wave * 16 + lr)) * 64;
    const unsigned short* q0r = q0 + qoff;
    const unsigned short* q1r = q1 + qoff;
#pragma unroll
    for (int kk = 0; kk < 2; ++kk) {
      ushort8 a0 = *(const ushort8*)&q0r[kk * 32 + lk];
      ushort8 a1 = *(const ushort8*)&q1r[kk * 32 + lk];
      short8 o;
#pragma unroll
      for (int j = 0; j < 8; ++j)
        o[j] = (short)f2bf(bf2f(a0[j]) + bf2f(a1[j]));
      qf[kk] = o;
    }
  }

  float m_run[4], l_run[4];
  f32x4 oacc[4];
#pragma unroll
  for (int r = 0; r < 4; ++r) { m_run[r] = -1e30f; l_run[r] = 0.f; }
#pragma unroll
  for (int nn = 0; nn < 4; ++nn) oacc[nn] = (f32x4){0.f, 0.f, 0.f, 0.f};

  int row_local = wave * 16 + lkg * 4;
  int krow_s = tid >> 1, kseg_s = (tid & 1) * 32;
  int t2 = tid & 127;
  int vr0 = (t2 & 15) * 4, vcs = (t2 >> 4) * 8;

  for (int st = 0; st <= qt; ++st) {
    int s0 = st << 6;
    if (tid < 128) {
      size_t koff = (size_t)(s0 + krow_s) * 64 + kseg_s;
#pragma unroll
      for (int i = 0; i < 4; ++i) {
        ushort8 a0 = *(const ushort8*)(kb0 + koff + i * 8);
        ushort8 a1 = *(const ushort8*)(kb1 + koff + i * 8);
        ushort8 o;
#pragma unroll
        for (int j = 0; j < 8; ++j) o[j] = f2bf(bf2f(a0[j]) + bf2f(a1[j]));
        *(ushort8*)&Ks[krow_s][kseg_s + i * 8] = o;
      }
    } else {
      ushort8 vr[4];
#pragma unroll
      for (int i = 0; i < 4; ++i) {
        size_t voff = (size_t)(s0 + vr0 + i) * 64 + vcs;
        ushort8 a0 = *(const ushort8*)(vb0 + voff);
        ushort8 a1 = *(const ushort8*)(vb1 + voff);
        ushort8 o;
#pragma unroll
        for (int j = 0; j < 8; ++j) o[j] = f2bf(bf2f(a0[j]) + bf2f(a1[j]));
        vr[i] = o;
      }
#pragma unroll
      for (int j = 0; j < 8; ++j) {
        ushort4v o = {vr[0][j], vr[1][j], vr[2][j], vr[3][j]};
        *(ushort4v*)&VTs[vcs + j][vr0] = o;
      }
    }
    __syncthreads();

    f32x4 sc[4] = {};
#pragma unroll
    for (int kk = 0; kk < 2; ++kk) {
#pragma unroll
      for (int nn = 0; nn < 4; ++nn) {
        short8 bfk = *(const short8*)&Ks[nn * 16 + lr][kk * 32 + lk];
        sc[nn] = __builtin_amdgcn_mfma_f32_16x16x32_bf16(qf[kk], bfk, sc[nn], 0, 0, 0);
      }
    }
    int r_base = s0 - t0 + 448;
    const unsigned short* kpb = kposb + (size_t)r_base * 1024 + h * 64;
    f32x4 srf[8] = {};
#pragma unroll
    for (int kk = 0; kk < 2; ++kk) {
#pragma unroll
      for (int nn = 0; nn < 8; ++nn) {
        short8 bfp = *(const short8*)&kpb[(size_t)(nn * 16 + lr) * 1024 + kk * 32 + lk];
        srf[nn] = __builtin_amdgcn_mfma_f32_16x16x32_bf16(qf[kk], bfp, srf[nn], 0, 0, 0);
      }
    }
#pragma unroll
    for (int nn = 0; nn < 8; ++nn)
#pragma unroll
      for (int r = 0; r < 4; ++r)
        Srl[row_local + r][nn * 16 + lr] = f2bf(srf[nn][r]);

    float sv[4][4];
#pragma unroll
    for (int nn = 0; nn < 4; ++nn) {
#pragma unroll
      for (int r = 0; r < 4; ++r) {
        int row = row_local + r;
        int scc = nn * 16 + lr;
        int rj = scc - row + 63;
        float spos = bf2f(Srl[row][rj]);
        float sval = (sc[nn][r] + spos) * 0.125f;
        sv[nn][r] = ((s0 + scc) <= (t0 + row)) ? sval : -1e9f;
      }
    }
    float alpha[4];
#pragma unroll
    for (int r = 0; r < 4; ++r) {
      float mx = fmaxf(fmaxf(sv[0][r], sv[1][r]), fmaxf(sv[2][r], sv[3][r]));
      mx = fmaxf(mx, __shfl_xor(mx, 1));
      mx = fmaxf(mx, __shfl_xor(mx, 2));
      mx = fmaxf(mx, __shfl_xor(mx, 4));
      mx = fmaxf(mx, __shfl_xor(mx, 8));
      float mn = fmaxf(m_run[r], mx);
      alpha[r] = __expf(m_run[r] - mn);
      m_run[r] = mn;
    }
    float psum[4] = {0.f, 0.f, 0.f, 0.f};
#pragma unroll
    for (int nn = 0; nn < 4; ++nn) {
#pragma unroll
      for (int r = 0; r < 4; ++r) {
        unsigned short pb = f2bf(__expf(sv[nn][r] - m_run[r]));
        Srl[row_local + r][64 + nn * 16 + lr] = pb;
        psum[r] += bf2f(pb);
      }
    }
#pragma unroll
    for (int r = 0; r < 4; ++r) {
      float s = psum[r];
      s += __shfl_xor(s, 1); s += __shfl_xor(s, 2);
      s += __shfl_xor(s, 4); s += __shfl_xor(s, 8);
      l_run[r] = l_run[r] * alpha[r] + s;
#pragma unroll
      for (int nn = 0; nn < 4; ++nn) oacc[nn][r] *= alpha[r];
    }
#pragma unroll
    for (int kk = 0; kk < 2; ++kk) {
      short8 pa = *(const short8*)&Srl[wave * 16 + lr][64 + kk * 32 + lk];
#pragma unroll
      for (int nn = 0; nn < 4; ++nn) {
        short8 bv = *(const short8*)&VTs[nn * 16 + lr][kk * 32 + lk];
        oacc[nn] = __builtin_amdgcn_mfma_f32_16x16x32_bf16(pa, bv, oacc[nn], 0, 0, 0);
      }
    }
    __syncthreads();
  }

#pragma unroll
  for (int r = 0; r < 4; ++r) {
    float inv = 1.f / l_run[r];
    int tg = t0 + row_local + r;
    unsigned short* crow = ctx + ((size_t)(b * T_ + tg) * H_ + h) * PV_;
#pragma unroll
    for (int nn = 0; nn < 4; ++nn)
      crow[nn * 16 + lr] = f2bf(oacc[nn][r] * inv);
  }
}

// ---------------------------------------------------------------- Wo transpose
__global__ __launch_bounds__(256) void wo_transpose_kernel(
    const float* __restrict__ Wo, __hip_bfloat16* __restrict__ Wob) {
  __shared__ float t[64][65];
  int kt = blockIdx.x, dt = blockIdx.y;
  int tid = threadIdx.x;
  int kr = tid >> 2, dseg = (tid & 3) * 16;
  const float4* src = (const float4*)&Wo[(size_t)(kt * 64 + kr) * 1024 + dt * 64 + dseg];
#pragma unroll
  for (int i = 0; i < 4; ++i) {
    float4 v4 = src[i];
    t[kr][dseg + i * 4 + 0] = v4.x;
    t[kr][dseg + i * 4 + 1] = v4.y;
    t[kr][dseg + i * 4 + 2] = v4.z;
    t[kr][dseg + i * 4 + 3] = v4.w;
  }
  __syncthreads();
  int dr = tid >> 2, kseg = (tid & 3) * 16;
  unsigned short* dst =
      (unsigned short*)Wob + (size_t)(dt * 64 + dr) * 8192 + kt * 64 + kseg;
#pragma unroll
  for (int half = 0; half < 2; ++half) {
    ushort8 o;
#pragma unroll
    for (int j = 0; j < 8; ++j) o[j] = f2bf(t[kseg + half * 8 + j][dr]);
    *(ushort8*)&dst[half * 8] = o;
  }
}

// ---------------------------------------------------------------- MoE out GEMM v5
__global__ __launch_bounds__(256) void moe_out_gemm(
    const __hip_bfloat16* __restrict__ ctx, const float* __restrict__ coefs,
    const __hip_bfloat16* __restrict__ Wob, float* __restrict__ out0,
    float* __restrict__ out1) {
  __shared__ __align__(16) unsigned short As[128][72];
  __shared__ __align__(16) unsigned short Bs[128][72];
  int tid = threadIdx.x;
  int nt = blockIdx.x, mt = blockIdx.y, zh = blockIdx.z;
  int wave = tid >> 6, lane = tid & 63;
  int wr = wave >> 1, wc = wave & 1;
  int lrow = lane & 15, lk = (lane >> 4) << 3;

  f32x4 acc[4][4] = {};

  int arow = tid >> 1, aseg = (tid & 1) * 32;
  const unsigned short* ctxu = (const unsigned short*)ctx;
  const unsigned short* wobu = (const unsigned short*)Wob;
  size_t grow = (size_t)mt * 128 + arow;
  const unsigned short* brp = &wobu[((size_t)nt * 128 + arow) * 8192 + aseg];
  int he0 = zh * 64;

  ushort8 ra[4], rb[4];
  float cf;
  {
    int h = he0 >> 3;
    const ushort8* a = (const ushort8*)&ctxu[(grow * 16 + h) * 64 + aseg];
    const ushort8* bp = (const ushort8*)&brp[(size_t)he0 * 64];
#pragma unroll
    for (int i = 0; i < 4; ++i) { ra[i] = a[i]; rb[i] = bp[i]; }
    cf = coefs[grow * 128 + he0];
  }

  for (int hh = 0; hh < 64; ++hh) {
#pragma unroll
    for (int i = 0; i < 4; ++i) {
      ushort8 o;
#pragma unroll
      for (int j = 0; j < 8; ++j) o[j] = f2bf(bf2f(ra[i][j]) * cf);
      *(ushort8*)&As[arow][aseg + i * 8] = o;
      *(ushort8*)&Bs[arow][aseg + i * 8] = rb[i];
    }
    __syncthreads();

    if (hh < 63) {
      int he = he0 + hh + 1;
      int h = he >> 3;
      const ushort8* a = (const ushort8*)&ctxu[(grow * 16 + h) * 64 + aseg];
      const ushort8* bp = (const ushort8*)&brp[(size_t)he * 64];
#pragma unroll
      for (int i = 0; i < 4; ++i) { ra[i] = a[i]; rb[i] = bp[i]; }
      cf = coefs[grow * 128 + he];
    }

    __builtin_amdgcn_s_setprio(1);
#pragma unroll
    for (int kk = 0; kk < 2; ++kk) {
      short8 af[4], bfr[4];
#pragma unroll
      for (int m = 0; m < 4; ++m)
        af[m] = *(const short8*)&As[wr * 64 + m * 16 + lrow][kk * 32 + lk];
#pragma unroll
      for (int n = 0; n < 4; ++n)
        bfr[n] = *(const short8*)&Bs[wc * 64 + n * 16 + lrow][kk * 32 + lk];
#pragma unroll
      for (int m = 0; m < 4; ++m)
#pragma unroll
        for (int n = 0; n < 4; ++n)
          acc[m][n] = __builtin_amdgcn_mfma_f32_16x16x32_bf16(
              af[m], bfr[n], acc[m][n], 0, 0, 0);
    }
    __builtin_amdgcn_s_setprio(0);
    __syncthreads();
  }

  float* outp = zh ? out1 : out0;
  int orow0 = mt * 128 + wr * 64 + (lane >> 4) * 4;
  int ocol0 = nt * 128 + wc * 64 + lrow;
#pragma unroll
  for (int m = 0; m < 4; ++m)
#pragma unroll
    for (int n = 0; n < 4; ++n)
#pragma unroll
      for (int r = 0; r < 4; ++r)
        outp[(size_t)(orow0 + m * 16 + r) * 1024 + ocol0 + n * 16] = acc[m][n][r];
}

// ---------------------------------------------------------------- final add
__global__ __launch_bounds__(256) void out_add_kernel(
    float* __restrict__ out, const float* __restrict__ out2) {
  int i = blockIdx.x * 256 + threadIdx.x;  // over 1M float4
  float4 a = ((const float4*)out)[i];
  float4 b = ((const float4*)out2)[i];
  a.x += b.x; a.y += b.y; a.z += b.z; a.w += b.w;
  ((float4*)out)[i] = a;
}

// ---------------------------------------------------------------- launch
extern "C" void kernel_launch(void* const* d_in, const int* in_sizes, int n_in,
                              void* d_out, int out_size, void* d_ws, size_t ws_size,
                              hipStream_t stream) {
  const float* x   = (const float*)d_in[0];
  const float* pe  = (const float*)d_in[1];
  const float* wso = (const float*)d_in[2];
  const float* wsv = (const float*)d_in[3];
  const float* Wq  = (const float*)d_in[4];
  const float* Wk  = (const float*)d_in[5];
  const float* Wv  = (const float*)d_in[6];
  const float* Wo  = (const float*)d_in[7];
  const float* Wp  = (const float*)d_in[8];
  float* out = (float*)d_out;
  char* ws = (char*)d_ws;

  // 64 MiB layout (proven available in R20)
  int*   cnt   = (int*)  (ws + 0);
  float* coefs = (float*)(ws + 4096);
  int*   lidx  = (int*)  (ws + 2101248);
  float* lg    = (float*)(ws + 4198400);
  unsigned short* xb    = (unsigned short*)(ws + 6295552);
  unsigned short* kposb = (unsigned short*)(ws + 14684160);
  unsigned short* q0    = (unsigned short*)(ws + 16781312);
  unsigned short* q1    = (unsigned short*)(ws + 25169920);
  unsigned short* k0    = (unsigned short*)(ws + 33558528);
  unsigned short* k1    = (unsigned short*)(ws + 41947136);
  unsigned short* v0    = (unsigned short*)(ws + 50335744);
  unsigned short* v1    = (unsigned short*)(ws + 58724352);
  // aliases
  float* part = (float*)(ws + 16781312);                  // over q0+q1 (pre-proj)
  float* wt   = (float*)(ws + 33558528);                  // over k0 (pre-proj)
  unsigned short* peb = (unsigned short*)(ws + 41947136); // over k1 (pre-proj)
  unsigned short* wpb = (unsigned short*)(ws + 44044288); // over k1 (pre-proj)
  unsigned short* Wvb = (unsigned short*)(ws + 33558528); // over k0+k1, consumed by proj(Wv)
  unsigned short* Wkb = (unsigned short*)(ws + 16781312); // over q0+q1, consumed by proj(Wk)
  __hip_bfloat16* ctx = (__hip_bfloat16*)(ws + 6295552);  // over xb (post-proj)
  __hip_bfloat16* Wob = (__hip_bfloat16*)(ws + 16781312); // over q0+q1 (post-attn)
  float* out2 = (float*)(ws + 33558528);                  // over k0+k1 (post-attn)

  hipLaunchKernelGGL(zero_cnt_kernel, dim3(1), dim3(512), 0, stream, cnt);
  hipLaunchKernelGGL(xcvt_kernel, dim3(4096), dim3(256), 0, stream, x, xb);
  hipLaunchKernelGGL(wt_transpose_kernel, dim3(4, 16), dim3(256), 0, stream,
                     wso, wsv, wt);
  hipLaunchKernelGGL(gates_gemm, dim3(128, 4), dim3(256), 0, stream,
                     x, wt, part);
  hipLaunchKernelGGL(gates_combine, dim3(512), dim3(256), 0, stream,
                     part, cnt, lidx, lg, coefs);

  hipLaunchKernelGGL(cvt_pos_kernel, dim3(R_ + 1024), dim3(256), 0, stream,
                     pe, Wp, peb, wpb);
  hipLaunchKernelGGL(kpos_mfma, dim3(9, 16), dim3(256), 0, stream,
                     peb, wpb, kposb);

  // bf16 weight conversions into dead regions; each consumed before overwrite:
  // Wvb over k0+k1 -> proj(Wv) (before proj(Wk) writes k0/k1);
  // Wkb over q0+q1 -> proj(Wk) (before proj(Wq) writes q0/q1).
  hipLaunchKernelGGL(wcvt_kernel, dim3(8192), dim3(256), 0, stream, Wv, Wvb);
  hipLaunchKernelGGL(proj_q2h_mfma, dim3(128, PTILES_), dim3(256), 0, stream,
                     xb, Wvb, cnt, lidx, lg, v0, v1, 1);
  hipLaunchKernelGGL(wcvt_kernel, dim3(8192), dim3(256), 0, stream, Wk, Wkb);
  hipLaunchKernelGGL(proj_q2h_mfma, dim3(128, PTILES_), dim3(256), 0, stream,
                     xb, Wkb, cnt, lidx, lg, k0, k1, 1);
  hipLaunchKernelGGL(proj_q2_mfma, dim3(128, PTILES_), dim3(256), 0, stream,
                     xb, Wq, cnt, lidx, lg, q0, q1, 0);

  hipLaunchKernelGGL(attn_mfma, dim3(B_, H_, 8), dim3(256), 0, stream,
                     q0, q1, k0, k1, v0, v1, kposb, (unsigned short*)ctx);

  hipLaunchKernelGGL(wo_transpose_kernel, dim3(128, 16), dim3(256), 0, stream,
                     Wo, Wob);
  hipLaunchKernelGGL(moe_out_gemm, dim3(8, 32, 2), dim3(256), 0, stream,
                     ctx, coefs, Wob, out, out2);
  hipLaunchKernelGGL(out_add_kernel, dim3(4096), dim3(256), 0, stream,
                     out, out2);
}

// Round 28
// 515.004 us; speedup vs baseline: 1.0408x; 1.0408x over previous
//
#include <hip/hip_runtime.h>
#include <hip/hip_bf16.h>
#include <math.h>

#define H_ 16
#define E_ 8
#define D_ 1024
#define P_ 64
#define PV_ 64
#define B_ 8
#define T_ 512
#define R_ 1023
#define BT_ 4096
#define CAP_ 1024
#define PROWS_ 192
#define PTILES_ 4

typedef __attribute__((ext_vector_type(8))) unsigned short ushort8;
typedef __attribute__((ext_vector_type(4))) unsigned short ushort4v;
typedef __attribute__((ext_vector_type(8))) short short8;
typedef __attribute__((ext_vector_type(4))) float f32x4;

__device__ inline float bf2f(unsigned short u) {
  union { unsigned int i; float f; } c; c.i = ((unsigned int)u) << 16; return c.f;
}
__device__ inline unsigned short f2bf(float f) {
  __hip_bfloat16 h = __float2bfloat16(f);
  return *reinterpret_cast<unsigned short*>(&h);
}

// ---------------------------------------------------------------- zero counts
__global__ void zero_cnt_kernel(int* __restrict__ cnt) {
  int i = threadIdx.x;
  if (i < 512) cnt[i] = 0;
}

// ---------------------------------------------------------------- x -> bf16
__global__ __launch_bounds__(256) void xcvt_kernel(
    const float* __restrict__ x, unsigned short* __restrict__ xbu) {
  int i = blockIdx.x * 256 + threadIdx.x;  // over 1M float4
  float4 w = ((const float4*)x)[i];
  ushort4v o = {f2bf(w.x), f2bf(w.y), f2bf(w.z), f2bf(w.w)};
  *(ushort4v*)&xbu[(size_t)i * 4] = o;
}

// ---------------------------------------------------------------- w_sel transpose
__global__ __launch_bounds__(256) void wt_transpose_kernel(
    const float* __restrict__ wso, const float* __restrict__ wsv,
    float* __restrict__ wt) {
  __shared__ float tb[64][65];
  int ct = blockIdx.x, kt = blockIdx.y;  // (4, 16)
  int tid = threadIdx.x;
  int cl = tid >> 2, kseg = (tid & 3) * 16;
  int c = ct * 64 + cl;
  const float* src = (c < 128) ? (wso + (size_t)c * D_)
                               : (wsv + (size_t)(c - 128) * D_);
#pragma unroll
  for (int i = 0; i < 4; ++i) {
    float4 v4 = *(const float4*)&src[kt * 64 + kseg + i * 4];
    tb[cl][kseg + i * 4 + 0] = v4.x;
    tb[cl][kseg + i * 4 + 1] = v4.y;
    tb[cl][kseg + i * 4 + 2] = v4.z;
    tb[cl][kseg + i * 4 + 3] = v4.w;
  }
  __syncthreads();
  int kl = tid >> 2, cseg = (tid & 3) * 16;
#pragma unroll
  for (int i = 0; i < 4; ++i) {
    float4 o = {tb[cseg + i * 4 + 0][kl], tb[cseg + i * 4 + 1][kl],
                tb[cseg + i * 4 + 2][kl], tb[cseg + i * 4 + 3][kl]};
    *(float4*)&wt[(size_t)(kt * 64 + kl) * 256 + ct * 64 + cseg + i * 4] = o;
  }
}

// ---------------------------------------------------------------- gates GEMM v4
__global__ __launch_bounds__(256) void gates_gemm(
    const float* __restrict__ x, const float* __restrict__ wt,
    float* __restrict__ part) {
  __shared__ __align__(16) float xs[32][256];  // 32 KB
  int tid = threadIdx.x;
  int bt0 = blockIdx.x * 32;
  int ks = blockIdx.y;

  {
    const float4* xr = (const float4*)x;
#pragma unroll
    for (int p = 0; p < 8; ++p) {
      int idx = p * 256 + tid;
      int r = idx >> 6, k4 = idx & 63;
      ((float4*)xs[r])[k4] = xr[(size_t)(bt0 + r) * 256 + ks * 64 + k4];
    }
  }
  __syncthreads();

  int wave = tid >> 6, lane = tid & 63;
  const float4* wt4 = (const float4*)wt + (size_t)ks * 256 * 64 + lane;
  float4 acc[8];
#pragma unroll
  for (int r = 0; r < 8; ++r) acc[r] = (float4){0.f, 0.f, 0.f, 0.f};

  for (int k4b = 0; k4b < 64; ++k4b) {
    float4 wv0 = wt4[(size_t)(k4b * 4 + 0) * 64];
    float4 wv1 = wt4[(size_t)(k4b * 4 + 1) * 64];
    float4 wv2 = wt4[(size_t)(k4b * 4 + 2) * 64];
    float4 wv3 = wt4[(size_t)(k4b * 4 + 3) * 64];
#pragma unroll
    for (int r = 0; r < 8; ++r) {
      float4 xv = ((const float4*)xs[wave * 8 + r])[k4b];
      acc[r].x += xv.x * wv0.x + xv.y * wv1.x + xv.z * wv2.x + xv.w * wv3.x;
      acc[r].y += xv.x * wv0.y + xv.y * wv1.y + xv.z * wv2.y + xv.w * wv3.y;
      acc[r].z += xv.x * wv0.z + xv.y * wv1.z + xv.z * wv2.z + xv.w * wv3.z;
      acc[r].w += xv.x * wv0.w + xv.y * wv1.w + xv.z * wv2.w + xv.w * wv3.w;
    }
  }

#pragma unroll
  for (int r = 0; r < 8; ++r)
    *(float4*)&part[((size_t)(bt0 + wave * 8 + r) * 4 + ks) * 256 + lane * 4] =
        acc[r];
}

// ---------------------------------------------------------------- gates combine
__global__ __launch_bounds__(256) void gates_combine(
    const float* __restrict__ part, int* __restrict__ cnt,
    int* __restrict__ lidx, float* __restrict__ lg,
    float* __restrict__ coefs) {
  __shared__ float gv[8][2][H_][E_];
  int tid = threadIdx.x;
  int bt0 = blockIdx.x * 8;

  {
    int set = tid >> 7, he = tid & 127;
    int h = he >> 3, e = he & 7;
#pragma unroll
    for (int r = 0; r < 8; ++r) {
      const float* p = &part[(size_t)(bt0 + r) * 4 * 256 + tid];
      float v = ((p[0] + p[256]) + p[512]) + p[768];
      gv[r][set][h][e] = 1.f / (1.f + expf(-v));
    }
  }
  __syncthreads();

  {
    int r = tid >> 5, st = (tid >> 4) & 1, hh = tid & 15;
    int bt = bt0 + r;
    const float* g = gv[r][st][hh];
    int i1 = 0; float v1 = g[0];
    for (int ee = 1; ee < 8; ee++) if (g[ee] > v1) { v1 = g[ee]; i1 = ee; }
    int i2 = (i1 == 0) ? 1 : 0; float v2 = g[i2];
    for (int ee = 0; ee < 8; ee++) {
      if (ee == i1) continue;
      if (g[ee] > v2) { v2 = g[ee]; i2 = ee; }
    }
    int base1 = ((st * H_ + hh) * E_ + i1) * 2 + 0;
    int p1 = atomicAdd(&cnt[base1], 1);
    lidx[(size_t)base1 * CAP_ + p1] = bt;
    lg[(size_t)base1 * CAP_ + p1] = v1;
    int base2 = ((st * H_ + hh) * E_ + i2) * 2 + 1;
    int p2 = atomicAdd(&cnt[base2], 1);
    lidx[(size_t)base2 * CAP_ + p2] = bt;
    lg[(size_t)base2 * CAP_ + p2] = v2;
    if (st == 0) {
#pragma unroll
      for (int ee = 0; ee < 8; ee++) {
        float c = (ee == i1) ? v1 : ((ee == i2) ? v2 : 0.f);
        coefs[((size_t)bt * H_ + hh) * E_ + ee] = c;
      }
    }
  }
}

// ---------------------------------------------------------------- proj both slots
// Stages one weight's B-tile once per K-step; both slots' A-tiles vs it.
// slot0 -> out0 ('='), slot1 -> out1 ('='); consumer sums.
__global__ __launch_bounds__(256) void proj_q2_mfma(
    const unsigned short* __restrict__ xb, const float* __restrict__ W,
    const int* __restrict__ cnt, const int* __restrict__ lidx,
    const float* __restrict__ lg, unsigned short* __restrict__ out0,
    unsigned short* __restrict__ out1, int set) {
  int he = blockIdx.x, tile = blockIdx.y;
  int base0 = (set * 128 + he) * 2 + 0, base1 = (set * 128 + he) * 2 + 1;
  int n0 = cnt[base0], n1 = cnt[base1];
  int start = tile * PROWS_;
  if (start >= n0 && start >= n1) return;
  int m0 = min(PROWS_, max(0, n0 - start));
  int m1 = min(PROWS_, max(0, n1 - start));

  __shared__ int ridx0[PROWS_], ridx1[PROWS_];
  __shared__ float rgs0[PROWS_], rgs1[PROWS_];
  __shared__ __align__(16) unsigned short As0[PROWS_][72];
  __shared__ __align__(16) unsigned short As1[PROWS_][72];
  __shared__ __align__(16) unsigned short Bs[64][72];
  int tid = threadIdx.x;
  for (int i = tid; i < PROWS_; i += 256) {
    int v0i = 0, v1i = 0; float g0 = 0.f, g1 = 0.f;
    if (i < m0) {
      v0i = lidx[(size_t)base0 * CAP_ + start + i];
      g0 = lg[(size_t)base0 * CAP_ + start + i];
    }
    if (i < m1) {
      v1i = lidx[(size_t)base1 * CAP_ + start + i];
      g1 = lg[(size_t)base1 * CAP_ + start + i];
    }
    ridx0[i] = v0i; rgs0[i] = g0;
    ridx1[i] = v1i; rgs1[i] = g1;
  }
  __syncthreads();

  int wave = tid >> 6, lane = tid & 63;
  int lr = lane & 15, lk = (lane >> 4) << 3;
  f32x4 acc0[3][4] = {}, acc1[3][4] = {};
  const float* Wb = W + (size_t)he * D_ * P_;

  int sr = tid >> 2, sseg = (tid & 3) << 4;
  int c4 = (tid & 15) * 4;
  int drb = tid >> 4;

  for (int d0 = 0; d0 < D_; d0 += 64) {
#pragma unroll
    for (int i = 0; i < 3; ++i) {
      int row = i * 64 + sr;
      const unsigned short* x0 = xb + (size_t)ridx0[row] * D_ + d0 + sseg;
      *(ushort8*)&As0[row][sseg] = *(const ushort8*)x0;
      *(ushort8*)&As0[row][sseg + 8] = *(const ushort8*)(x0 + 8);
      const unsigned short* x1 = xb + (size_t)ridx1[row] * D_ + d0 + sseg;
      *(ushort8*)&As1[row][sseg] = *(const ushort8*)x1;
      *(ushort8*)&As1[row][sseg + 8] = *(const ushort8*)(x1 + 8);
    }
#pragma unroll
    for (int pass = 0; pass < 4; ++pass) {
      int dr = pass * 16 + drb;
      float4 wv = *(const float4*)&Wb[(size_t)(d0 + dr) * P_ + c4];
      Bs[c4 + 0][dr] = f2bf(wv.x);
      Bs[c4 + 1][dr] = f2bf(wv.y);
      Bs[c4 + 2][dr] = f2bf(wv.z);
      Bs[c4 + 3][dr] = f2bf(wv.w);
    }
    __syncthreads();
#pragma unroll
    for (int kk = 0; kk < 2; ++kk) {
      short8 af0[3], af1[3], bfr[4];
#pragma unroll
      for (int mm = 0; mm < 3; ++mm) {
        af0[mm] = *(const short8*)&As0[wave * 48 + mm * 16 + lr][kk * 32 + lk];
        af1[mm] = *(const short8*)&As1[wave * 48 + mm * 16 + lr][kk * 32 + lk];
      }
#pragma unroll
      for (int nn = 0; nn < 4; ++nn)
        bfr[nn] = *(const short8*)&Bs[nn * 16 + lr][kk * 32 + lk];
#pragma unroll
      for (int mm = 0; mm < 3; ++mm)
#pragma unroll
        for (int nn = 0; nn < 4; ++nn) {
          acc0[mm][nn] = __builtin_amdgcn_mfma_f32_16x16x32_bf16(
              af0[mm], bfr[nn], acc0[mm][nn], 0, 0, 0);
          acc1[mm][nn] = __builtin_amdgcn_mfma_f32_16x16x32_bf16(
              af1[mm], bfr[nn], acc1[mm][nn], 0, 0, 0);
        }
    }
    __syncthreads();
  }

  int h = he >> 3;
#pragma unroll
  for (int mm = 0; mm < 3; ++mm) {
#pragma unroll
    for (int r = 0; r < 4; ++r) {
      int row = wave * 48 + mm * 16 + (lane >> 4) * 4 + r;
      if (row < m0) {
        int bt = ridx0[row]; float g = rgs0[row];
        int b = bt >> 9, t = bt & 511;
        unsigned short* orow = out0 + ((size_t)((b * H_ + h) * T_) + t) * P_;
#pragma unroll
        for (int nn = 0; nn < 4; ++nn)
          orow[nn * 16 + lr] = f2bf(g * acc0[mm][nn][r]);
      }
      if (row < m1) {
        int bt = ridx1[row]; float g = rgs1[row];
        int b = bt >> 9, t = bt & 511;
        unsigned short* orow = out1 + ((size_t)((b * H_ + h) * T_) + t) * P_;
#pragma unroll
        for (int nn = 0; nn < 4; ++nn)
          orow[nn * 16 + lr] = f2bf(g * acc1[mm][nn][r]);
      }
    }
  }
}

// ---------------------------------------------------------------- pe/Wpos -> bf16
__global__ __launch_bounds__(256) void cvt_pos_kernel(
    const float* __restrict__ pe, const float* __restrict__ Wp,
    unsigned short* __restrict__ peb, unsigned short* __restrict__ wpb) {
  int bid = blockIdx.x;
  const float* src;
  unsigned short* dst;
  if (bid < R_) { src = pe + (size_t)bid * D_; dst = peb + (size_t)bid * D_; }
  else { src = Wp + (size_t)(bid - R_) * D_; dst = wpb + (size_t)(bid - R_) * D_; }
  int tid = threadIdx.x;
  float4 w = ((const float4*)src)[tid];
  ushort4v o = {f2bf(w.x), f2bf(w.y), f2bf(w.z), f2bf(w.w)};
  *(ushort4v*)&dst[tid * 4] = o;
}

// ---------------------------------------------------------------- k_pos MFMA v2
__global__ __launch_bounds__(256) void kpos_mfma(
    const unsigned short* __restrict__ peb, const unsigned short* __restrict__ wpb,
    unsigned short* __restrict__ kposb) {
  __shared__ __align__(16) unsigned short As[64][72];
  __shared__ __align__(16) unsigned short Bs[64][72];
  int tid = threadIdx.x, mt = blockIdx.x, nt = blockIdx.y;
  int wave = tid >> 6, lane = tid & 63;
  int wr = wave >> 1, wc = wave & 1;
  int lrow = lane & 15, lk = (lane >> 4) << 3;
  f32x4 acc[2][2] = {};
  int sr = tid >> 2, sseg = (tid & 3) << 4;

  for (int d0 = 0; d0 < D_; d0 += 64) {
    {
      const unsigned short* arow = &peb[(size_t)(mt * 64 + sr) * D_ + d0 + sseg];
      *(ushort8*)&As[sr][sseg] = *(const ushort8*)arow;
      *(ushort8*)&As[sr][sseg + 8] = *(const ushort8*)(arow + 8);
      const unsigned short* brow = &wpb[(size_t)(nt * 64 + sr) * D_ + d0 + sseg];
      *(ushort8*)&Bs[sr][sseg] = *(const ushort8*)brow;
      *(ushort8*)&Bs[sr][sseg + 8] = *(const ushort8*)(brow + 8);
    }
    __syncthreads();
#pragma unroll
    for (int kk = 0; kk < 2; ++kk) {
      short8 af[2], bfr[2];
#pragma unroll
      for (int mm = 0; mm < 2; ++mm)
        af[mm] = *(const short8*)&As[wr * 32 + mm * 16 + lrow][kk * 32 + lk];
#pragma unroll
      for (int nn = 0; nn < 2; ++nn)
        bfr[nn] = *(const short8*)&Bs[wc * 32 + nn * 16 + lrow][kk * 32 + lk];
#pragma unroll
      for (int mm = 0; mm < 2; ++mm)
#pragma unroll
        for (int nn = 0; nn < 2; ++nn)
          acc[mm][nn] = __builtin_amdgcn_mfma_f32_16x16x32_bf16(
              af[mm], bfr[nn], acc[mm][nn], 0, 0, 0);
    }
    __syncthreads();
  }

  int orow0 = mt * 64 + wr * 32 + (lane >> 4) * 4;
  int ocol0 = nt * 64 + wc * 32 + lrow;
#pragma unroll
  for (int mm = 0; mm < 2; ++mm)
#pragma unroll
    for (int nn = 0; nn < 2; ++nn)
#pragma unroll
      for (int r = 0; r < 4; ++r)
        kposb[(size_t)(orow0 + mm * 16 + r) * 1024 + ocol0 + nn * 16] =
            f2bf(acc[mm][nn][r]);
}

// ---------------------------------------------------------------- attention (MFMA flash)
// q = q0+q1, k = k0+k1, v = v0+v1 (summed while staging).
__global__ __launch_bounds__(256) void attn_mfma(
    const unsigned short* __restrict__ q0, const unsigned short* __restrict__ q1,
    const unsigned short* __restrict__ k0, const unsigned short* __restrict__ k1,
    const unsigned short* __restrict__ v0, const unsigned short* __restrict__ v1,
    const unsigned short* __restrict__ kposb, unsigned short* __restrict__ ctx) {
  int b = blockIdx.x, h = blockIdx.y, qt = blockIdx.z;
  int t0 = qt << 6;
  int tid = threadIdx.x, wave = tid >> 6, lane = tid & 63;
  int lr = lane & 15, lkg = lane >> 4;
  int lk = lkg << 3;

  __shared__ __align__(16) unsigned short Ks[64][72];
  __shared__ __align__(16) unsigned short VTs[64][72];
  __shared__ __align__(16) unsigned short Srl[64][136];

  size_t bh = (size_t)(b * H_ + h);
  const unsigned short* kb0 = k0 + bh * T_ * 64;
  const unsigned short* kb1 = k1 + bh * T_ * 64;
  const unsigned short* vb0 = v0 + bh * T_ * 64;
  const unsigned short* vb1 = v1 + bh * T_ * 64;

  short8 qf[2];
  {
    size_t qoff = (bh * T_ + (size_t)(t0 + wave * 16 + lr)) * 64;
    const unsigned short* q0r = q0 + qoff;
    const unsigned short* q1r = q1 + qoff;
#pragma unroll
    for (int kk = 0; kk < 2; ++kk) {
      ushort8 a0 = *(const ushort8*)&q0r[kk * 32 + lk];
      ushort8 a1 = *(const ushort8*)&q1r[kk * 32 + lk];
      short8 o;
#pragma unroll
      for (int j = 0; j < 8; ++j)
        o[j] = (short)f2bf(bf2f(a0[j]) + bf2f(a1[j]));
      qf[kk] = o;
    }
  }

  float m_run[4], l_run[4];
  f32x4 oacc[4];
#pragma unroll
  for (int r = 0; r < 4; ++r) { m_run[r] = -1e30f; l_run[r] = 0.f; }
#pragma unroll
  for (int nn = 0; nn < 4; ++nn) oacc[nn] = (f32x4){0.f, 0.f, 0.f, 0.f};

  int row_local = wave * 16 + lkg * 4;
  int krow_s = tid >> 1, kseg_s = (tid & 1) * 32;
  int t2 = tid & 127;
  int vr0 = (t2 & 15) * 4, vcs = (t2 >> 4) * 8;

  for (int st = 0; st <= qt; ++st) {
    int s0 = st << 6;
    if (tid < 128) {
      size_t koff = (size_t)(s0 + krow_s) * 64 + kseg_s;
#pragma unroll
      for (int i = 0; i < 4; ++i) {
        ushort8 a0 = *(const ushort8*)(kb0 + koff + i * 8);
        ushort8 a1 = *(const ushort8*)(kb1 + koff + i * 8);
        ushort8 o;
#pragma unroll
        for (int j = 0; j < 8; ++j) o[j] = f2bf(bf2f(a0[j]) + bf2f(a1[j]));
        *(ushort8*)&Ks[krow_s][kseg_s + i * 8] = o;
      }
    } else {
      ushort8 vr[4];
#pragma unroll
      for (int i = 0; i < 4; ++i) {
        size_t voff = (size_t)(s0 + vr0 + i) * 64 + vcs;
        ushort8 a0 = *(const ushort8*)(vb0 + voff);
        ushort8 a1 = *(const ushort8*)(vb1 + voff);
        ushort8 o;
#pragma unroll
        for (int j = 0; j < 8; ++j) o[j] = f2bf(bf2f(a0[j]) + bf2f(a1[j]));
        vr[i] = o;
      }
#pragma unroll
      for (int j = 0; j < 8; ++j) {
        ushort4v o = {vr[0][j], vr[1][j], vr[2][j], vr[3][j]};
        *(ushort4v*)&VTs[vcs + j][vr0] = o;
      }
    }
    __syncthreads();

    f32x4 sc[4] = {};
#pragma unroll
    for (int kk = 0; kk < 2; ++kk) {
#pragma unroll
      for (int nn = 0; nn < 4; ++nn) {
        short8 bfk = *(const short8*)&Ks[nn * 16 + lr][kk * 32 + lk];
        sc[nn] = __builtin_amdgcn_mfma_f32_16x16x32_bf16(qf[kk], bfk, sc[nn], 0, 0, 0);
      }
    }
    int r_base = s0 - t0 + 448;
    const unsigned short* kpb = kposb + (size_t)r_base * 1024 + h * 64;
    f32x4 srf[8] = {};
#pragma unroll
    for (int kk = 0; kk < 2; ++kk) {
#pragma unroll
      for (int nn = 0; nn < 8; ++nn) {
        short8 bfp = *(const short8*)&kpb[(size_t)(nn * 16 + lr) * 1024 + kk * 32 + lk];
        srf[nn] = __builtin_amdgcn_mfma_f32_16x16x32_bf16(qf[kk], bfp, srf[nn], 0, 0, 0);
      }
    }
#pragma unroll
    for (int nn = 0; nn < 8; ++nn)
#pragma unroll
      for (int r = 0; r < 4; ++r)
        Srl[row_local + r][nn * 16 + lr] = f2bf(srf[nn][r]);

    float sv[4][4];
#pragma unroll
    for (int nn = 0; nn < 4; ++nn) {
#pragma unroll
      for (int r = 0; r < 4; ++r) {
        int row = row_local + r;
        int scc = nn * 16 + lr;
        int rj = scc - row + 63;
        float spos = bf2f(Srl[row][rj]);
        float sval = (sc[nn][r] + spos) * 0.125f;
        sv[nn][r] = ((s0 + scc) <= (t0 + row)) ? sval : -1e9f;
      }
    }
    float alpha[4];
#pragma unroll
    for (int r = 0; r < 4; ++r) {
      float mx = fmaxf(fmaxf(sv[0][r], sv[1][r]), fmaxf(sv[2][r], sv[3][r]));
      mx = fmaxf(mx, __shfl_xor(mx, 1));
      mx = fmaxf(mx, __shfl_xor(mx, 2));
      mx = fmaxf(mx, __shfl_xor(mx, 4));
      mx = fmaxf(mx, __shfl_xor(mx, 8));
      float mn = fmaxf(m_run[r], mx);
      alpha[r] = __expf(m_run[r] - mn);
      m_run[r] = mn;
    }
    float psum[4] = {0.f, 0.f, 0.f, 0.f};
#pragma unroll
    for (int nn = 0; nn < 4; ++nn) {
#pragma unroll
      for (int r = 0; r < 4; ++r) {
        unsigned short pb = f2bf(__expf(sv[nn][r] - m_run[r]));
        Srl[row_local + r][64 + nn * 16 + lr] = pb;
        psum[r] += bf2f(pb);
      }
    }
#pragma unroll
    for (int r = 0; r < 4; ++r) {
      float s = psum[r];
      s += __shfl_xor(s, 1); s += __shfl_xor(s, 2);
      s += __shfl_xor(s, 4); s += __shfl_xor(s, 8);
      l_run[r] = l_run[r] * alpha[r] + s;
#pragma unroll
      for (int nn = 0; nn < 4; ++nn) oacc[nn][r] *= alpha[r];
    }
#pragma unroll
    for (int kk = 0; kk < 2; ++kk) {
      short8 pa = *(const short8*)&Srl[wave * 16 + lr][64 + kk * 32 + lk];
#pragma unroll
      for (int nn = 0; nn < 4; ++nn) {
        short8 bv = *(const short8*)&VTs[nn * 16 + lr][kk * 32 + lk];
        oacc[nn] = __builtin_amdgcn_mfma_f32_16x16x32_bf16(pa, bv, oacc[nn], 0, 0, 0);
      }
    }
    __syncthreads();
  }

#pragma unroll
  for (int r = 0; r < 4; ++r) {
    float inv = 1.f / l_run[r];
    int tg = t0 + row_local + r;
    unsigned short* crow = ctx + ((size_t)(b * T_ + tg) * H_ + h) * PV_;
#pragma unroll
    for (int nn = 0; nn < 4; ++nn)
      crow[nn * 16 + lr] = f2bf(oacc[nn][r] * inv);
  }
}

// ---------------------------------------------------------------- Wo transpose
__global__ __launch_bounds__(256) void wo_transpose_kernel(
    const float* __restrict__ Wo, __hip_bfloat16* __restrict__ Wob) {
  __shared__ float t[64][65];
  int kt = blockIdx.x, dt = blockIdx.y;
  int tid = threadIdx.x;
  int kr = tid >> 2, dseg = (tid & 3) * 16;
  const float4* src = (const float4*)&Wo[(size_t)(kt * 64 + kr) * 1024 + dt * 64 + dseg];
#pragma unroll
  for (int i = 0; i < 4; ++i) {
    float4 v4 = src[i];
    t[kr][dseg + i * 4 + 0] = v4.x;
    t[kr][dseg + i * 4 + 1] = v4.y;
    t[kr][dseg + i * 4 + 2] = v4.z;
    t[kr][dseg + i * 4 + 3] = v4.w;
  }
  __syncthreads();
  int dr = tid >> 2, kseg = (tid & 3) * 16;
  unsigned short* dst =
      (unsigned short*)Wob + (size_t)(dt * 64 + dr) * 8192 + kt * 64 + kseg;
#pragma unroll
  for (int half = 0; half < 2; ++half) {
    ushort8 o;
#pragma unroll
    for (int j = 0; j < 8; ++j) o[j] = f2bf(t[kseg + half * 8 + j][dr]);
    *(ushort8*)&dst[half * 8] = o;
  }
}

// ---------------------------------------------------------------- MoE out GEMM v5
__global__ __launch_bounds__(256) void moe_out_gemm(
    const __hip_bfloat16* __restrict__ ctx, const float* __restrict__ coefs,
    const __hip_bfloat16* __restrict__ Wob, float* __restrict__ out0,
    float* __restrict__ out1) {
  __shared__ __align__(16) unsigned short As[128][72];
  __shared__ __align__(16) unsigned short Bs[128][72];
  int tid = threadIdx.x;
  int nt = blockIdx.x, mt = blockIdx.y, zh = blockIdx.z;
  int wave = tid >> 6, lane = tid & 63;
  int wr = wave >> 1, wc = wave & 1;
  int lrow = lane & 15, lk = (lane >> 4) << 3;

  f32x4 acc[4][4] = {};

  int arow = tid >> 1, aseg = (tid & 1) * 32;
  const unsigned short* ctxu = (const unsigned short*)ctx;
  const unsigned short* wobu = (const unsigned short*)Wob;
  size_t grow = (size_t)mt * 128 + arow;
  const unsigned short* brp = &wobu[((size_t)nt * 128 + arow) * 8192 + aseg];
  int he0 = zh * 64;

  ushort8 ra[4], rb[4];
  float cf;
  {
    int h = he0 >> 3;
    const ushort8* a = (const ushort8*)&ctxu[(grow * 16 + h) * 64 + aseg];
    const ushort8* bp = (const ushort8*)&brp[(size_t)he0 * 64];
#pragma unroll
    for (int i = 0; i < 4; ++i) { ra[i] = a[i]; rb[i] = bp[i]; }
    cf = coefs[grow * 128 + he0];
  }

  for (int hh = 0; hh < 64; ++hh) {
#pragma unroll
    for (int i = 0; i < 4; ++i) {
      ushort8 o;
#pragma unroll
      for (int j = 0; j < 8; ++j) o[j] = f2bf(bf2f(ra[i][j]) * cf);
      *(ushort8*)&As[arow][aseg + i * 8] = o;
      *(ushort8*)&Bs[arow][aseg + i * 8] = rb[i];
    }
    __syncthreads();

    if (hh < 63) {
      int he = he0 + hh + 1;
      int h = he >> 3;
      const ushort8* a = (const ushort8*)&ctxu[(grow * 16 + h) * 64 + aseg];
      const ushort8* bp = (const ushort8*)&brp[(size_t)he * 64];
#pragma unroll
      for (int i = 0; i < 4; ++i) { ra[i] = a[i]; rb[i] = bp[i]; }
      cf = coefs[grow * 128 + he];
    }

    __builtin_amdgcn_s_setprio(1);
#pragma unroll
    for (int kk = 0; kk < 2; ++kk) {
      short8 af[4], bfr[4];
#pragma unroll
      for (int m = 0; m < 4; ++m)
        af[m] = *(const short8*)&As[wr * 64 + m * 16 + lrow][kk * 32 + lk];
#pragma unroll
      for (int n = 0; n < 4; ++n)
        bfr[n] = *(const short8*)&Bs[wc * 64 + n * 16 + lrow][kk * 32 + lk];
#pragma unroll
      for (int m = 0; m < 4; ++m)
#pragma unroll
        for (int n = 0; n < 4; ++n)
          acc[m][n] = __builtin_amdgcn_mfma_f32_16x16x32_bf16(
              af[m], bfr[n], acc[m][n], 0, 0, 0);
    }
    __builtin_amdgcn_s_setprio(0);
    __syncthreads();
  }

  float* outp = zh ? out1 : out0;
  int orow0 = mt * 128 + wr * 64 + (lane >> 4) * 4;
  int ocol0 = nt * 128 + wc * 64 + lrow;
#pragma unroll
  for (int m = 0; m < 4; ++m)
#pragma unroll
    for (int n = 0; n < 4; ++n)
#pragma unroll
      for (int r = 0; r < 4; ++r)
        outp[(size_t)(orow0 + m * 16 + r) * 1024 + ocol0 + n * 16] = acc[m][n][r];
}

// ---------------------------------------------------------------- final add
__global__ __launch_bounds__(256) void out_add_kernel(
    float* __restrict__ out, const float* __restrict__ out2) {
  int i = blockIdx.x * 256 + threadIdx.x;  // over 1M float4
  float4 a = ((const float4*)out)[i];
  float4 b = ((const float4*)out2)[i];
  a.x += b.x; a.y += b.y; a.z += b.z; a.w += b.w;
  ((float4*)out)[i] = a;
}

// ---------------------------------------------------------------- launch
extern "C" void kernel_launch(void* const* d_in, const int* in_sizes, int n_in,
                              void* d_out, int out_size, void* d_ws, size_t ws_size,
                              hipStream_t stream) {
  const float* x   = (const float*)d_in[0];
  const float* pe  = (const float*)d_in[1];
  const float* wso = (const float*)d_in[2];
  const float* wsv = (const float*)d_in[3];
  const float* Wq  = (const float*)d_in[4];
  const float* Wk  = (const float*)d_in[5];
  const float* Wv  = (const float*)d_in[6];
  const float* Wo  = (const float*)d_in[7];
  const float* Wp  = (const float*)d_in[8];
  float* out = (float*)d_out;
  char* ws = (char*)d_ws;

  // 64 MiB layout (proven available in R20)
  int*   cnt   = (int*)  (ws + 0);
  float* coefs = (float*)(ws + 4096);
  int*   lidx  = (int*)  (ws + 2101248);
  float* lg    = (float*)(ws + 4198400);
  unsigned short* xb    = (unsigned short*)(ws + 6295552);
  unsigned short* kposb = (unsigned short*)(ws + 14684160);
  unsigned short* q0    = (unsigned short*)(ws + 16781312);
  unsigned short* q1    = (unsigned short*)(ws + 25169920);
  unsigned short* k0    = (unsigned short*)(ws + 33558528);
  unsigned short* k1    = (unsigned short*)(ws + 41947136);
  unsigned short* v0    = (unsigned short*)(ws + 50335744);
  unsigned short* v1    = (unsigned short*)(ws + 58724352);
  // aliases
  float* part = (float*)(ws + 16781312);                  // over q0+q1 (pre-proj)
  float* wt   = (float*)(ws + 33558528);                  // over k0 (pre-proj)
  unsigned short* peb = (unsigned short*)(ws + 41947136); // over k1 (pre-proj)
  unsigned short* wpb = (unsigned short*)(ws + 44044288); // over k1 (pre-proj)
  __hip_bfloat16* ctx = (__hip_bfloat16*)(ws + 6295552);  // over xb (post-proj)
  __hip_bfloat16* Wob = (__hip_bfloat16*)(ws + 16781312); // over q0+q1 (post-attn)
  float* out2 = (float*)(ws + 33558528);                  // over k0+k1 (post-attn)

  hipLaunchKernelGGL(zero_cnt_kernel, dim3(1), dim3(512), 0, stream, cnt);
  hipLaunchKernelGGL(xcvt_kernel, dim3(4096), dim3(256), 0, stream, x, xb);
  hipLaunchKernelGGL(wt_transpose_kernel, dim3(4, 16), dim3(256), 0, stream,
                     wso, wsv, wt);
  hipLaunchKernelGGL(gates_gemm, dim3(128, 4), dim3(256), 0, stream,
                     x, wt, part);
  hipLaunchKernelGGL(gates_combine, dim3(512), dim3(256), 0, stream,
                     part, cnt, lidx, lg, coefs);

  hipLaunchKernelGGL(cvt_pos_kernel, dim3(R_ + 1024), dim3(256), 0, stream,
                     pe, Wp, peb, wpb);
  hipLaunchKernelGGL(kpos_mfma, dim3(9, 16), dim3(256), 0, stream,
                     peb, wpb, kposb);

  hipLaunchKernelGGL(proj_q2_mfma, dim3(128, PTILES_), dim3(256), 0, stream,
                     xb, Wq, cnt, lidx, lg, q0, q1, 0);
  hipLaunchKernelGGL(proj_q2_mfma, dim3(128, PTILES_), dim3(256), 0, stream,
                     xb, Wk, cnt, lidx, lg, k0, k1, 1);
  hipLaunchKernelGGL(proj_q2_mfma, dim3(128, PTILES_), dim3(256), 0, stream,
                     xb, Wv, cnt, lidx, lg, v0, v1, 1);

  hipLaunchKernelGGL(attn_mfma, dim3(B_, H_, 8), dim3(256), 0, stream,
                     q0, q1, k0, k1, v0, v1, kposb, (unsigned short*)ctx);

  hipLaunchKernelGGL(wo_transpose_kernel, dim3(128, 16), dim3(256), 0, stream,
                     Wo, Wob);
  hipLaunchKernelGGL(moe_out_gemm, dim3(8, 32, 2), dim3(256), 0, stream,
                     ctx, coefs, Wob, out, out2);
  hipLaunchKernelGGL(out_add_kernel, dim3(4096), dim3(256), 0, stream,
                     out, out2);
}